// Round 4
// baseline (271.799 us; speedup 1.0000x reference)
//
#include <hip/hip_runtime.h>
#include <math.h>

// Problem constants
#define D0 32
#define D1 256
#define D2 256
#define HS2 129            // rfft half-spectrum last dim
#define NVOX (D0*D1*D2)    // 2097152
#define KMAX 4
#define NK 9               // k in [-4,4]
#define NK2 5              // k2 in [0,4]
#define NCH 3
#define BATCH 4
#define FCH 3
#define NBC (BATCH*FCH)    // 12
#define C_FLOATS (NCH*NK*NK*NK2*2)   // 2430
// S layout: [zy][32] floats; slot = ch*10 + k2*2 + reim  (30 used, pad to 32)

typedef float v2f __attribute__((ext_vector_type(2)));

// ROUND 4:
// R3 (plain stores + L3 warm) was the first real win: deform 128 -> 82.7us,
// VALUBusy 46%, FETCH ~= fr footprint (102MB). Remaining deform stall ~50%:
// ~24 resident waves/CU x 12 outstanding loads = 288 in flight covering
// ~700cy L3 latency -> concurrency-limited reads. Fixes this round:
//  (a) warm_l3 was latency-bound (1 load + asm consumer per iter -> one
//      vmcnt round-trip per 16B): ~38us for a 16us stream. Rewrite with 12
//      independent loads in flight per thread -> ~17us.
//  (b) deform: TWO adjacent rows (z,y),(z,y+1) per wave, all 24 gathers
//      issued before the first wait (sched_barrier pins order; consume A at
//      vmcnt(12), then B). Outstanding/CU ~576 = 2x. Also shares the x-trig
//      and makes the two S-rows one contiguous scalar-load region.
// Predict: deform 82.7 -> 58-68us, VGPR ~70, VALU 55-70%, traffic unchanged.

// Dense stream of fr (100.7MB) into L3. 2048 blocks x 256 thr = 524288
// threads; n4 = 6291456 float4 = exactly 12/thread. 12 independent loads
// in flight per thread, one drain at the end.
__global__ __launch_bounds__(256) void warm_l3(
    const float4* __restrict__ fr4)
{
    int tid = blockIdx.x * 256 + threadIdx.x;
    const int stride = 2048 * 256;
    float ax = 0.f, ay = 0.f, az = 0.f, aw = 0.f;
    #pragma unroll
    for (int k = 0; k < 12; ++k) {
        float4 v = fr4[tid + k * stride];
        ax += v.x; ay += v.y; az += v.z; aw += v.w;
    }
    asm volatile("" :: "v"(ax), "v"(ay), "v"(az), "v"(aw));
}

// 256 blocks x 256 threads: build dense C cube in LDS (scatter, ~fdim loads),
// then 32 zy rows/block, 81-mode sum split 8 ways across consecutive lanes,
// width-8 shuffle reduction.
__global__ __launch_bounds__(256) void build_S(
    const float* __restrict__ seeds, const float* __restrict__ Pk,
    const float* __restrict__ defscale, const int* __restrict__ feed_idx,
    int fdim, float* __restrict__ S)
{
    __shared__ float C[C_FLOATS];
    __shared__ int fed[NK*NK];
    int t = threadIdx.x;
    for (int i = t; i < C_FLOATS; i += 256) C[i] = 0.0f;
    if (t < NK*NK) fed[t] = 0;
    __syncthreads();
    float ds0 = defscale[0], ds1 = defscale[1], ds2 = defscale[2];
    const int STR_RI = D0 * D1 * HS2;   // 1056768
    const int STR_A  = D1 * HS2;        // 33024
    for (int j = t; j < fdim; j += 256) {
        int idx = feed_idx[j];
        int ri = idx / STR_RI; int r = idx - ri * STR_RI;
        int a  = r / STR_A;    r -= a * STR_A;
        int b  = r / HS2;      int c = r - b * HS2;
        int k0 = (a < D0/2) ? a : a - D0;
        int k1 = (b < D1/2) ? b : b - D1;
        if (k0 < -KMAX || k0 > KMAX || k1 < -KMAX || k1 > KMAX || c > KMAX) continue;
        int i0 = k0 + KMAX, i1 = k1 + KMAX;
        float pk = Pk[j];
        int base = ((i0*NK + i1)*NK2 + c)*2 + ri;
        C[base]                 = seeds[0*fdim + j] * pk * ds0;
        C[base + 1*NK*NK*NK2*2] = seeds[1*fdim + j] * pk * ds1;
        C[base + 2*NK*NK*NK2*2] = seeds[2*fdim + j] * pk * ds2;
        if (c == 0) fed[i0*NK + i1] = 1;
    }
    __syncthreads();
    // hermitian completion on the k2=0 plane: unfed <- conj(mirror)
    if (t < NK*NK && !fed[t]) {
        int i0 = t / NK, i1 = t - i0*NK;
        int m0 = (NK-1) - i0, m1 = (NK-1) - i1;
        for (int ch = 0; ch < NCH; ++ch) {
            int dst = ((ch*NK*NK + i0*NK + i1)*NK2 + 0)*2;
            int src = ((ch*NK*NK + m0*NK + m1)*NK2 + 0)*2;
            C[dst]   = C[src];
            C[dst+1] = -C[src+1];
        }
    }
    __syncthreads();

    int zyl = t >> 3;           // 0..31  (consecutive lanes share zyl)
    int g   = t & 7;            // mode group 0..7
    int zy = blockIdx.x * 32 + zyl;
    int z = zy >> 8, y = zy & 255;

    float w0r[NK], w0i[NK], w1r[NK], w1i[NK];
    {
        float th = (float)z * (6.28318530717958647692f / (float)D0);
        float sb, cb; __sincosf(th, &sb, &cb);
        w0r[KMAX] = 1.0f; w0i[KMAX] = 0.0f;
        float pr = 1.0f, pi = 0.0f;
        #pragma unroll
        for (int k = 1; k <= KMAX; ++k) {
            float nr = pr*cb - pi*sb, ni = pr*sb + pi*cb;
            pr = nr; pi = ni;
            w0r[KMAX+k] = pr; w0i[KMAX+k] = pi;
            w0r[KMAX-k] = pr; w0i[KMAX-k] = -pi;
        }
    }
    {
        float th = (float)y * (6.28318530717958647692f / (float)D1);
        float sb, cb; __sincosf(th, &sb, &cb);
        w1r[KMAX] = 1.0f; w1i[KMAX] = 0.0f;
        float pr = 1.0f, pi = 0.0f;
        #pragma unroll
        for (int k = 1; k <= KMAX; ++k) {
            float nr = pr*cb - pi*sb, ni = pr*sb + pi*cb;
            pr = nr; pi = ni;
            w1r[KMAX+k] = pr; w1i[KMAX+k] = pi;
            w1r[KMAX-k] = pr; w1i[KMAX-k] = -pi;
        }
    }

    float Sr[NCH*NK2], Si[NCH*NK2];
    #pragma unroll
    for (int i = 0; i < NCH*NK2; ++i) { Sr[i] = 0.0f; Si[i] = 0.0f; }

    for (int m = g; m < NK*NK; m += 8) {
        int i0 = m / NK, i1 = m - i0*NK;
        float Tr = w0r[i0]*w1r[i1] - w0i[i0]*w1i[i1];
        float Ti = w0r[i0]*w1i[i1] + w0i[i0]*w1r[i1];
        const float* Cp = C + m*NK2*2;
        #pragma unroll
        for (int ch = 0; ch < NCH; ++ch) {
            #pragma unroll
            for (int k2 = 0; k2 < NK2; ++k2) {
                float cr = Cp[ch*(NK*NK*NK2*2) + k2*2];
                float ci = Cp[ch*(NK*NK*NK2*2) + k2*2 + 1];
                int o = ch*NK2 + k2;
                Sr[o] += cr*Tr - ci*Ti;
                Si[o] += cr*Ti + ci*Tr;
            }
        }
    }

    #pragma unroll
    for (int off = 4; off >= 1; off >>= 1) {
        #pragma unroll
        for (int i = 0; i < NCH*NK2; ++i) {
            Sr[i] += __shfl_down(Sr[i], off, 8);
            Si[i] += __shfl_down(Si[i], off, 8);
        }
    }

    if (g == 0) {
        const float invN = 1.0f / (float)NVOX;
        float* Sp = S + (size_t)zy * 32;
        #pragma unroll
        for (int ch = 0; ch < NCH; ++ch) {
            #pragma unroll
            for (int k2 = 0; k2 < NK2; ++k2) {
                int o = ch*NK2 + k2;
                float sc = (k2 == 0) ? invN : 2.0f*invN;
                Sp[ch*10 + k2*2 + 0] = Sr[o] * sc;
                Sp[ch*10 + k2*2 + 1] = Si[o] * sc;
            }
        }
    }
}

// Two adjacent y-rows per wave; all 24 gathers in flight before first wait.
__global__ __launch_bounds__(256) void deform_sample(
    const float* __restrict__ fr, const float* __restrict__ S,
    float* __restrict__ out)
{
    int i = blockIdx.x;                 // 16384 blocks
    int u = i & 7;                      // XCD id = unit id (dispatch i%8)
    int b  = u >> 1;                    // batch (channel group) 0..3
    int zh = u & 1;                     // z-half 0..1
    int j = i >> 3;                     // 0..2047; y-pair sweeps fastest
    int z = (zh << 4) + (j >> 7);
    int yA = (j & 127) << 1;
    int yB = yA + 1;
    int zyA = (z << 8) + yA;
    int x = threadIdx.x;

    // 2 x 30 wave-uniform coefficients; rows adjacent -> one contiguous
    // 64-float scalar-load region.
    const float* __restrict__ Sp = S + (size_t)zyA * 32;
    float sA[30], sB[30];
    #pragma unroll
    for (int q = 0; q < 30; ++q) sA[q] = Sp[q];
    #pragma unroll
    for (int q = 0; q < 30; ++q) sB[q] = Sp[32 + q];

    // cos/sin(k*theta), theta = 2*pi*x/256 -- shared by both rows
    float th = (float)x * (6.28318530717958647692f / (float)D2);
    float sb, cb; __sincosf(th, &sb, &cb);
    float ckr[KMAX], cks[KMAX];
    ckr[0] = cb; cks[0] = sb;
    #pragma unroll
    for (int k = 1; k < KMAX; ++k) {
        float nr = ckr[k-1]*cb - cks[k-1]*sb;
        float ni = cks[k-1]*cb + ckr[k-1]*sb;
        ckr[k] = nr; cks[k] = ni;
    }

    float dA[NCH], dB[NCH];
    #pragma unroll
    for (int ch = 0; ch < NCH; ++ch) {
        float aA = sA[ch*10 + 0];
        float aB = sB[ch*10 + 0];
        #pragma unroll
        for (int k = 1; k <= KMAX; ++k) {
            aA += sA[ch*10 + k*2]*ckr[k-1] - sA[ch*10 + k*2 + 1]*cks[k-1];
            aB += sB[ch*10 + k*2]*ckr[k-1] - sB[ch*10 + k*2 + 1]*cks[k-1];
        }
        dA[ch] = aA; dB[ch] = aB;
    }

    // ---- row A address math ----
    float fzA = fminf(fmaxf((float)z  - dA[0], 0.0f), (float)(D0-1));
    float fyA = fminf(fmaxf((float)yA - dA[1], 0.0f), (float)(D1-1));
    float fxA = fminf(fmaxf((float)x  - dA[2], 0.0f), (float)(D2-1));
    float z0fA = floorf(fzA), y0fA = floorf(fyA), x0fA = floorf(fxA);
    int z0A = (int)z0fA, y0A = (int)y0fA, x0A = (int)x0fA;
    int z1A = min(z0A + 1, D0-1), y1A = min(y0A + 1, D1-1);
    float wzA = fzA - z0fA, wyA = fyA - y0fA, wxA = fxA - x0fA;
    int xmA = min(x0A, D2-2);
    bool hiA = (x0A > xmA);
    int o00A = (z0A << 16) + (y0A << 8) + xmA;
    int o01A = (z0A << 16) + (y1A << 8) + xmA;
    int o10A = (z1A << 16) + (y0A << 8) + xmA;
    int o11A = (z1A << 16) + (y1A << 8) + xmA;

    // ---- row B address math ----
    float fzB = fminf(fmaxf((float)z  - dB[0], 0.0f), (float)(D0-1));
    float fyB = fminf(fmaxf((float)yB - dB[1], 0.0f), (float)(D1-1));
    float fxB = fminf(fmaxf((float)x  - dB[2], 0.0f), (float)(D2-1));
    float z0fB = floorf(fzB), y0fB = floorf(fyB), x0fB = floorf(fxB);
    int z0B = (int)z0fB, y0B = (int)y0fB, x0B = (int)x0fB;
    int z1B = min(z0B + 1, D0-1), y1B = min(y0B + 1, D1-1);
    float wzB = fzB - z0fB, wyB = fyB - y0fB, wxB = fxB - x0fB;
    int xmB = min(x0B, D2-2);
    bool hiB = (x0B > xmB);
    int o00B = (z0B << 16) + (y0B << 8) + xmB;
    int o01B = (z0B << 16) + (y1B << 8) + xmB;
    int o10B = (z1B << 16) + (y0B << 8) + xmB;
    int o11B = (z1B << 16) + (y1B << 8) + xmB;

    // ---- issue all 24 gathers before any consume ----
    const float* __restrict__ vb = fr + ((size_t)(b*FCH) << 21);
    v2f PA[FCH][4], PB[FCH][4];
    #pragma unroll
    for (int c = 0; c < FCH; ++c) {
        const float* __restrict__ v = vb + ((size_t)c << 21);
        PA[c][0] = *(const v2f*)(v + o00A);
        PA[c][1] = *(const v2f*)(v + o01A);
        PA[c][2] = *(const v2f*)(v + o10A);
        PA[c][3] = *(const v2f*)(v + o11A);
    }
    #pragma unroll
    for (int c = 0; c < FCH; ++c) {
        const float* __restrict__ v = vb + ((size_t)c << 21);
        PB[c][0] = *(const v2f*)(v + o00B);
        PB[c][1] = *(const v2f*)(v + o01B);
        PB[c][2] = *(const v2f*)(v + o10B);
        PB[c][3] = *(const v2f*)(v + o11B);
    }
    // pin: no consume (and its implied wait) may move above the issues;
    // consuming A then needs only vmcnt(12) -- B's 12 stay in flight.
    __builtin_amdgcn_sched_barrier(0);

    size_t ob = ((size_t)(b*FCH) << 21) + ((size_t)zyA << 8) + x;

    // ---- consume A ----
    #pragma unroll
    for (int c = 0; c < FCH; ++c) {
        float a00 = hiA ? PA[c][0].y : PA[c][0].x;
        float a01 = hiA ? PA[c][1].y : PA[c][1].x;
        float a10 = hiA ? PA[c][2].y : PA[c][2].x;
        float a11 = hiA ? PA[c][3].y : PA[c][3].x;
        float c00 = a00 + wxA * (PA[c][0].y - a00);
        float c01 = a01 + wxA * (PA[c][1].y - a01);
        float c10 = a10 + wxA * (PA[c][2].y - a10);
        float c11 = a11 + wxA * (PA[c][3].y - a11);
        float c0 = c00 + wyA * (c01 - c00);
        float c1 = c10 + wyA * (c11 - c10);
        out[ob + ((size_t)c << 21)] = c0 + wzA * (c1 - c0);
    }
    __builtin_amdgcn_sched_barrier(0);

    // ---- consume B ----
    #pragma unroll
    for (int c = 0; c < FCH; ++c) {
        float a00 = hiB ? PB[c][0].y : PB[c][0].x;
        float a01 = hiB ? PB[c][1].y : PB[c][1].x;
        float a10 = hiB ? PB[c][2].y : PB[c][2].x;
        float a11 = hiB ? PB[c][3].y : PB[c][3].x;
        float c00 = a00 + wxB * (PB[c][0].y - a00);
        float c01 = a01 + wxB * (PB[c][1].y - a01);
        float c10 = a10 + wxB * (PB[c][2].y - a10);
        float c11 = a11 + wxB * (PB[c][3].y - a11);
        float c0 = c00 + wyB * (c01 - c00);
        float c1 = c10 + wyB * (c11 - c10);
        out[ob + 256 + ((size_t)c << 21)] = c0 + wzB * (c1 - c0);
    }
}

extern "C" void kernel_launch(void* const* d_in, const int* in_sizes, int n_in,
                              void* d_out, int out_size, void* d_ws, size_t ws_size,
                              hipStream_t stream) {
    const float* fr       = (const float*)d_in[0];
    const float* seeds    = (const float*)d_in[1];
    const float* Pk       = (const float*)d_in[2];
    const float* defscale = (const float*)d_in[3];
    // d_in[4] = grid (values are exactly meshgrid(arange) -> recomputed in-kernel)
    const int*   feed_idx = (const int*)d_in[5];
    int fdim = in_sizes[2];

    float* S = (float*)d_ws;   // 8192 * 32 floats = 1 MB

    // Warm L3 with a dense sequential read of fr (100.7 MB): scattered
    // deform reads then hit L3 at stable latency.
    warm_l3<<<2048, 256, 0, stream>>>((const float4*)fr);
    build_S<<<256, 256, 0, stream>>>(seeds, Pk, defscale, feed_idx, fdim, S);
    deform_sample<<<16384, 256, 0, stream>>>(fr, S, (float*)d_out);
}